// Round 2
// baseline (256.342 us; speedup 1.0000x reference)
//
#include <hip/hip_runtime.h>
#include <hip/hip_bf16.h>
#include <math.h>

// Problem constants (B=2, C=128, G=16, Cg=8, K=3, H=W=192)
#define BB 2
#define CC 128
#define GG 16
#define CG 8
#define HH 192
#define WW 192
#define HM 190
#define WM 190
#define LL (HM * WM)          // 36100
#define HWSZ (HH * WW)        // 36864
#define NTRIPLE (BB * GG * 9) // 288

// Scratch lives in OUR module, not the harness workspace (d_ws size is not
// guaranteed; writing past it corrupted the harness's pristine input copy in
// R0 -> post-timing divergence). Phase1 fully rewrites these every call
// before phase2 reads them (same stream), so every call does identical work.
__device__ int g_umax[NTRIPLE];
__device__ float g_cmax[NTRIPLE];

// -------- Phase 1: per (b,g,j) Gram matrix -> nn_idx -> u_max, c_max --------
// One block (256 threads) per (b,g,j). The 8 vectors (d=0..7) are shifted
// views of 1-2 channels: f=j*8+d, channel=f/9, kernel offset k=f%9.
__global__ __launch_bounds__(256) void phase1_kernel(
    const float* __restrict__ feat) {
  const int bid = blockIdx.x; // 0..287
  const int b = bid / (GG * 9);
  const int rem = bid % (GG * 9);
  const int g = rem / 9;
  const int j = rem % 9;

  const float* base[8];
#pragma unroll
  for (int d = 0; d < 8; ++d) {
    const int f = j * 8 + d;
    const int c = f / 9;
    const int k = f % 9;
    const int ki = k / 3, kj = k % 3;
    base[d] = feat + (size_t)(b * CC + g * CG + c) * HWSZ + ki * WW + kj;
  }

  float sq[8];
  float gram[28];
#pragma unroll
  for (int i = 0; i < 8; ++i) sq[i] = 0.0f;
#pragma unroll
  for (int i = 0; i < 28; ++i) gram[i] = 0.0f;

  for (int l = threadIdx.x; l < LL; l += 256) {
    const int y = l / WM;
    const int x = l - y * WM;
    const int off = y * WW + x;
    float v[8];
#pragma unroll
    for (int d = 0; d < 8; ++d) v[d] = base[d][off];
#pragma unroll
    for (int d = 0; d < 8; ++d) sq[d] += v[d] * v[d];
    int p = 0;
#pragma unroll
    for (int c = 0; c < 8; ++c)
#pragma unroll
      for (int d = c + 1; d < 8; ++d) gram[p++] += v[c] * v[d];
  }

  // Block reduction: wave shuffle (64 lanes) then LDS across 4 waves.
  __shared__ float red[36 * 4];
  const int lane = threadIdx.x & 63;
  const int wave = threadIdx.x >> 6;
#pragma unroll
  for (int i = 0; i < 8; ++i) {
    float v = sq[i];
    for (int o = 32; o > 0; o >>= 1) v += __shfl_down(v, o, 64);
    if (lane == 0) red[i * 4 + wave] = v;
  }
#pragma unroll
  for (int i = 0; i < 28; ++i) {
    float v = gram[i];
    for (int o = 32; o > 0; o >>= 1) v += __shfl_down(v, o, 64);
    if (lane == 0) red[(8 + i) * 4 + wave] = v;
  }
  __syncthreads();

  if (threadIdx.x == 0) {
    float s[8], gm[8][8];
    for (int i = 0; i < 8; ++i)
      s[i] = red[i * 4] + red[i * 4 + 1] + red[i * 4 + 2] + red[i * 4 + 3];
    int p = 0;
    for (int c = 0; c < 8; ++c)
      for (int d = c + 1; d < 8; ++d) {
        const float v = red[(8 + p) * 4] + red[(8 + p) * 4 + 1] +
                        red[(8 + p) * 4 + 2] + red[(8 + p) * 4 + 3];
        gm[c][d] = v;
        gm[d][c] = v;
        ++p;
      }
    // per-row argmin with inf diagonal, first-occurrence tie-break
    int nn[8];
    for (int c = 0; c < 8; ++c) {
      float best = INFINITY;
      int bi = 0;
      for (int d = 0; d < 8; ++d) {
        if (d == c) continue;
        const float d2 = s[c] + s[d] - 2.0f * gm[c][d];
        if (d2 < best) {
          best = d2;
          bi = d;
        }
      }
      nn[c] = bi;
    }
    int um = 0;
    for (int c = 0; c < 8; ++c) um = um > nn[c] ? um : nn[c];
    int cnt = 0;
    for (int c = 0; c < 8; ++c) cnt += (nn[c] == um) ? 1 : 0;
    g_umax[bid] = um;
    g_cmax[bid] = (float)cnt;
  }
}

// -------- Phase 2: one thread per output element --------
// out[b,ch,h,w] = (b!=0 ? n_valid*v : 0) + sum_k floor(v * v_nn * c_max / 8)
__global__ __launch_bounds__(256) void phase2_kernel(
    const float* __restrict__ feat, float* __restrict__ out) {
  const int idx = blockIdx.x * 256 + threadIdx.x;
  if (idx >= BB * CC * HWSZ) return;
  const int w = idx % WW;
  int t = idx / WW;
  const int h = t % HH;
  t /= HH;
  const int ch = t % CC;
  const int b = t / CC;
  const int g = ch >> 3;
  const int cl = ch & 7;

  const float v = feat[idx];
  float acc = 0.0f;
  int nvalid = 0;
  const int bg9 = (b * GG + g) * 9;
  const size_t chan_base = (size_t)(b * CC + g * CG) * HWSZ;

#pragma unroll
  for (int k = 0; k < 9; ++k) {
    const int ki = k / 3, kj = k % 3;
    const int y = h - ki, x = w - kj;
    if ((unsigned)y < (unsigned)HM && (unsigned)x < (unsigned)WM) {
      ++nvalid;
      const int f = cl * 9 + k;
      const int j = f >> 3;
      const int um = g_umax[bg9 + j];
      const float cm = g_cmax[bg9 + j];
      const int fn = j * 8 + um;
      const int cn = fn / 9;
      const int kn = fn % 9;
      const int kin = kn / 3, kjn = kn % 3;
      const float vn =
          feat[chan_base + (size_t)cn * HWSZ + (y + kin) * WW + (x + kjn)];
      // exact fp32 op order of the reference: ((v*vn)*cm)/8 then floor
      float tv = v * vn;
      tv = tv * cm;
      tv = tv * 0.125f; // /8 is a power of two: exact
      acc += floorf(tv);
    }
  }
  if (b != 0) acc += (float)nvalid * v;
  out[idx] = acc;
}

extern "C" void kernel_launch(void* const* d_in, const int* in_sizes, int n_in,
                              void* d_out, int out_size, void* d_ws,
                              size_t ws_size, hipStream_t stream) {
  const float* feat = (const float*)d_in[0];
  float* out = (float*)d_out;
  (void)d_ws;
  (void)ws_size;

  phase1_kernel<<<NTRIPLE, 256, 0, stream>>>(feat);

  const int total = BB * CC * HWSZ;
  phase2_kernel<<<(total + 255) / 256, 256, 0, stream>>>(feat, out);
}

// Round 3
// 153.661 us; speedup vs baseline: 1.6682x; 1.6682x over previous
//
#include <hip/hip_runtime.h>
#include <hip/hip_bf16.h>
#include <math.h>

// Problem constants (B=2, C=128, G=16, Cg=8, K=3, H=W=192)
#define BB 2
#define CC 128
#define GG 16
#define CG 8
#define HH 192
#define WW 192
#define HM 190
#define WM 190
#define LL (HM * WM)          // 36100
#define HWSZ (HH * WW)        // 36864
#define NTRIPLE (BB * GG * 9) // 288

// Per-(b,g,f=cl*9+k) tables produced by phase1, consumed by phase2.
// rel_off: neighbor element offset relative to the query pixel
//          (cn-cl)*HWSZ + (kin-ki)*WW + (kjn-kj)  -- constant over (h,w).
// scale:   c_max * 0.125f  (exact: int times power of two).
// These live in OUR module (d_ws size unverified; writing it corrupted the
// pristine input copy in R0). Phase1 fully rewrites them every call before
// phase2 reads them (same stream) -> identical work every call.
__device__ int g_rel[BB * GG * 72];
__device__ float g_scl[BB * GG * 72];

// -------- Phase 1: per (b,g,j) Gram matrix -> argmin -> table entries -----
// One block of 1024 threads (16 waves) per (b,g,j): 16 waves/CU for latency
// hiding (the 256-thread version ran at 1 wave/SIMD and was latency-bound).
__global__ __launch_bounds__(1024) void phase1_kernel(
    const float* __restrict__ feat) {
  const int bid = blockIdx.x; // 0..287
  const int b = bid / (GG * 9);
  const int rem = bid % (GG * 9);
  const int g = rem / 9;
  const int j = rem % 9;

  const float* base[8];
#pragma unroll
  for (int d = 0; d < 8; ++d) {
    const int f = j * 8 + d;
    const int c = f / 9;
    const int k = f % 9;
    const int ki = k / 3, kj = k % 3;
    base[d] = feat + (size_t)(b * CC + g * CG + c) * HWSZ + ki * WW + kj;
  }

  float sq[8];
  float gram[28];
#pragma unroll
  for (int i = 0; i < 8; ++i) sq[i] = 0.0f;
#pragma unroll
  for (int i = 0; i < 28; ++i) gram[i] = 0.0f;

  for (int l = threadIdx.x; l < LL; l += 1024) {
    const int y = l / WM;
    const int x = l - y * WM;
    const int off = y * WW + x;
    float v[8];
#pragma unroll
    for (int d = 0; d < 8; ++d) v[d] = base[d][off];
#pragma unroll
    for (int d = 0; d < 8; ++d) sq[d] += v[d] * v[d];
    int p = 0;
#pragma unroll
    for (int c = 0; c < 8; ++c)
#pragma unroll
      for (int d = c + 1; d < 8; ++d) gram[p++] += v[c] * v[d];
  }

  // Block reduction: wave shuffle (64 lanes) then LDS across 16 waves.
  __shared__ float red[36 * 16];
  __shared__ float tot[36];
  const int lane = threadIdx.x & 63;
  const int wave = threadIdx.x >> 6;
#pragma unroll
  for (int i = 0; i < 8; ++i) {
    float v = sq[i];
    for (int o = 32; o > 0; o >>= 1) v += __shfl_down(v, o, 64);
    if (lane == 0) red[i * 16 + wave] = v;
  }
#pragma unroll
  for (int i = 0; i < 28; ++i) {
    float v = gram[i];
    for (int o = 32; o > 0; o >>= 1) v += __shfl_down(v, o, 64);
    if (lane == 0) red[(8 + i) * 16 + wave] = v;
  }
  __syncthreads();
  if (threadIdx.x < 36) {
    float s = 0.0f;
#pragma unroll
    for (int t = 0; t < 16; ++t) s += red[threadIdx.x * 16 + t];
    tot[threadIdx.x] = s;
  }
  __syncthreads();

  if (threadIdx.x == 0) {
    float s[8], gm[8][8];
    for (int i = 0; i < 8; ++i) s[i] = tot[i];
    int p = 0;
    for (int c = 0; c < 8; ++c)
      for (int d = c + 1; d < 8; ++d) {
        gm[c][d] = tot[8 + p];
        gm[d][c] = tot[8 + p];
        ++p;
      }
    // per-row argmin with inf diagonal, first-occurrence tie-break
    int nn[8];
    for (int c = 0; c < 8; ++c) {
      float best = INFINITY;
      int bi = 0;
      for (int d = 0; d < 8; ++d) {
        if (d == c) continue;
        const float d2 = s[c] + s[d] - 2.0f * gm[c][d];
        if (d2 < best) {
          best = d2;
          bi = d;
        }
      }
      nn[c] = bi;
    }
    int um = 0;
    for (int c = 0; c < 8; ++c) um = um > nn[c] ? um : nn[c];
    int cnt = 0;
    for (int c = 0; c < 8; ++c) cnt += (nn[c] == um) ? 1 : 0;

    // Emit phase2 table entries for the 8 f's owned by this triple.
    // f in [8j, 8j+8) -> f>>3 == j, so the query (cl=f/9,k=f%9) uses this
    // triple's (um, cnt).
    const float sc = (float)cnt * 0.125f;
    const int fn = j * 8 + um;
    const int cn = fn / 9;
    const int kn = fn % 9;
    const int kin = kn / 3, kjn = kn % 3;
    for (int d = 0; d < 8; ++d) {
      const int f = j * 8 + d;
      const int cl = f / 9;
      const int k = f % 9;
      const int ki = k / 3, kj = k % 3;
      const int rel = (cn - cl) * HWSZ + (kin - ki) * WW + (kjn - kj);
      const int tix = (b * GG + g) * 72 + f;
      g_rel[tix] = rel;
      g_scl[tix] = sc;
    }
  }
}

// -------- Phase 2: one thread per output element, table-driven ------------
// out[b,ch,h,w] = (b!=0 ? n_valid*v : 0) + sum_k floor(v * v_nn * cm / 8)
// Block covers 256 consecutive pixels of ONE plane (HWSZ % 256 == 0), so
// (b,ch) and the 9 table entries are block-uniform (scalar loads).
__global__ __launch_bounds__(256) void phase2_kernel(
    const float* __restrict__ feat, float* __restrict__ out) {
  const int BLOCKS_PER_PLANE = HWSZ / 256; // 144
  const int plane = blockIdx.x / BLOCKS_PER_PLANE;   // b*CC + ch
  const int within = blockIdx.x % BLOCKS_PER_PLANE;
  const int b = plane / CC;
  const int ch = plane % CC;
  const int g = ch >> 3;
  const int cl = ch & 7;

  const int pix = within * 256 + (int)threadIdx.x;
  const int h = pix / WW;
  const int w = pix % WW;
  const int idx = plane * HWSZ + pix;

  const int tbase = (b * GG + g) * 72 + cl * 9; // block-uniform
  int off[9];
  float scl[9];
#pragma unroll
  for (int k = 0; k < 9; ++k) {
    off[k] = g_rel[tbase + k];
    scl[k] = g_scl[tbase + k];
  }

  const float v = feat[idx];
  const float* basep = feat + idx;
  float acc = 0.0f;
  int nv = 0;
#pragma unroll
  for (int k = 0; k < 9; ++k) {
    const int ki = k / 3, kj = k % 3; // compile-time
    const bool valid = (h >= ki) & (h < HM + ki) & (w >= kj) & (w < WM + kj);
    const int o = valid ? off[k] : 0; // clamp: keep the load in-bounds
    const float vn = basep[o];
    // exact fp32 op order of the reference: round(v*vn * cm)/8 ==
    // round(v*vn * (cm/8)) since /8 is an exact exponent shift.
    float tv = v * vn;
    tv = tv * scl[k];
    const float fl = floorf(tv);
    acc += valid ? fl : 0.0f;
    nv += valid ? 1 : 0;
  }
  if (b != 0) acc += (float)nv * v;
  out[idx] = acc;
}

extern "C" void kernel_launch(void* const* d_in, const int* in_sizes, int n_in,
                              void* d_out, int out_size, void* d_ws,
                              size_t ws_size, hipStream_t stream) {
  const float* feat = (const float*)d_in[0];
  float* out = (float*)d_out;
  (void)d_ws;
  (void)ws_size;

  phase1_kernel<<<NTRIPLE, 1024, 0, stream>>>(feat);

  const int total = BB * CC * HWSZ;
  phase2_kernel<<<total / 256, 256, 0, stream>>>(feat, out);
}

// Round 4
// 145.699 us; speedup vs baseline: 1.7594x; 1.0546x over previous
//
#include <hip/hip_runtime.h>
#include <hip/hip_bf16.h>
#include <math.h>

// Problem constants (B=2, C=128, G=16, Cg=8, K=3, H=W=192)
#define BB 2
#define CC 128
#define GG 16
#define CG 8
#define HH 192
#define WW 192
#define HM 190
#define WM 190
#define LL (HM * WM)          // 36100
#define HWSZ (HH * WW)        // 36864
#define NTRIPLE (BB * GG * 9) // 288
#define SPLIT 6               // L-dim slices for phase1 parallelism
#define SLICE_LEN ((LL + SPLIT - 1) / SPLIT) // 6017

// Module-owned scratch (d_ws size unverified; writing it corrupted the
// harness pristine input copy in R0). Everything below is fully rewritten
// on every call before being read (same stream) -> identical work per call.
__device__ float g_part[NTRIPLE * SPLIT * 36]; // per-slice partial sums
__device__ int g_rel[BB * GG * 72];            // phase2: neighbor rel offset
__device__ float g_scl[BB * GG * 72];          // phase2: c_max/8

// -------- Phase 1a: per (b,g,j,slice) partial Gram sums -------------------
// 1728 blocks x 256 threads (~27 waves/CU, balanced). Each block reduces
// SLICE_LEN pixels into 36 sums (8 squares + 28 cross products).
__global__ __launch_bounds__(256) void phase1a_kernel(
    const float* __restrict__ feat) {
  const int tri = blockIdx.x / SPLIT; // 0..287
  const int sl = blockIdx.x % SPLIT;
  const int b = tri / (GG * 9);
  const int rem = tri % (GG * 9);
  const int g = rem / 9;
  const int j = rem % 9;

  const float* base[8];
#pragma unroll
  for (int d = 0; d < 8; ++d) {
    const int f = j * 8 + d;
    const int c = f / 9;
    const int k = f % 9;
    const int ki = k / 3, kj = k % 3;
    base[d] = feat + (size_t)(b * CC + g * CG + c) * HWSZ + ki * WW + kj;
  }

  float acc[36];
#pragma unroll
  for (int i = 0; i < 36; ++i) acc[i] = 0.0f;

  const int l0 = sl * SLICE_LEN;
  const int l1 = (l0 + SLICE_LEN < LL) ? (l0 + SLICE_LEN) : LL;
  for (int l = l0 + (int)threadIdx.x; l < l1; l += 256) {
    const int y = l / WM;
    const int x = l - y * WM;
    const int off = y * WW + x;
    float v[8];
#pragma unroll
    for (int d = 0; d < 8; ++d) v[d] = base[d][off];
#pragma unroll
    for (int d = 0; d < 8; ++d) acc[d] += v[d] * v[d];
    int p = 8;
#pragma unroll
    for (int c = 0; c < 8; ++c)
#pragma unroll
      for (int d = c + 1; d < 8; ++d) acc[p++] += v[c] * v[d];
  }

  // Wave shuffle reduce (64 lanes) then LDS across 4 waves.
  __shared__ float red[36 * 4];
  const int lane = threadIdx.x & 63;
  const int wave = threadIdx.x >> 6;
#pragma unroll
  for (int i = 0; i < 36; ++i) {
    float v = acc[i];
    for (int o = 32; o > 0; o >>= 1) v += __shfl_down(v, o, 64);
    if (lane == 0) red[i * 4 + wave] = v;
  }
  __syncthreads();
  if (threadIdx.x < 36) {
    const int i = threadIdx.x;
    g_part[(tri * SPLIT + sl) * 36 + i] =
        red[i * 4] + red[i * 4 + 1] + red[i * 4 + 2] + red[i * 4 + 3];
  }
}

// -------- Phase 1b: reduce slices, 8x8 argmin, emit phase2 tables ---------
__global__ __launch_bounds__(64) void phase1b_kernel() {
  const int tri = blockIdx.x * 64 + (int)threadIdx.x;
  if (tri >= NTRIPLE) return;
  const int b = tri / (GG * 9);
  const int rem = tri % (GG * 9);
  const int g = rem / 9;
  const int j = rem % 9;

  float tot[36];
#pragma unroll
  for (int i = 0; i < 36; ++i) tot[i] = 0.0f;
  for (int s = 0; s < SPLIT; ++s)
#pragma unroll
    for (int i = 0; i < 36; ++i) tot[i] += g_part[(tri * SPLIT + s) * 36 + i];

  float sq[8], gm[8][8];
#pragma unroll
  for (int i = 0; i < 8; ++i) sq[i] = tot[i];
  {
    int p = 8;
    for (int c = 0; c < 8; ++c)
      for (int d = c + 1; d < 8; ++d) {
        gm[c][d] = tot[p];
        gm[d][c] = tot[p];
        ++p;
      }
  }
  // per-row argmin with inf diagonal, first-occurrence tie-break
  int nn[8];
  for (int c = 0; c < 8; ++c) {
    float best = INFINITY;
    int bi = 0;
    for (int d = 0; d < 8; ++d) {
      if (d == c) continue;
      const float d2 = sq[c] + sq[d] - 2.0f * gm[c][d];
      if (d2 < best) {
        best = d2;
        bi = d;
      }
    }
    nn[c] = bi;
  }
  int um = 0;
  for (int c = 0; c < 8; ++c) um = um > nn[c] ? um : nn[c];
  int cnt = 0;
  for (int c = 0; c < 8; ++c) cnt += (nn[c] == um) ? 1 : 0;

  // Table entries for the 8 f's owned by this triple (f=8j+d -> f>>3==j).
  // scale = c_max/8 (exact: int * power of two); rel = neighbor offset
  // relative to the query pixel, constant over (h,w).
  const float sc = (float)cnt * 0.125f;
  const int fn = j * 8 + um;
  const int cn = fn / 9;
  const int kn = fn % 9;
  const int kin = kn / 3, kjn = kn % 3;
  for (int d = 0; d < 8; ++d) {
    const int f = j * 8 + d;
    const int cl = f / 9;
    const int k = f % 9;
    const int ki = k / 3, kj = k % 3;
    const int rel = (cn - cl) * HWSZ + (kin - ki) * WW + (kjn - kj);
    const int tix = (b * GG + g) * 72 + f;
    g_rel[tix] = rel;
    g_scl[tix] = sc;
  }
}

// -------- Phase 2: wave-per-row, table-driven -----------------------------
// out[b,ch,h,w] = (b!=0 ? n_valid*v : 0) + sum_k floor(v * v_nn * cm / 8)
// Each wave owns one 192-px row: h and the 9 table entries are wave-uniform
// (scalar branch skips invalid k's on border rows). Lane covers x = lane,
// lane+64, lane+128; the middle segment is never w-invalid and kj is
// compile-time, so edge masks are 1-2 cndmasks per k.
__global__ __launch_bounds__(256) void phase2_kernel(
    const float* __restrict__ feat, float* __restrict__ out) {
  const int row = blockIdx.x * 4 + ((int)threadIdx.x >> 6); // plane*HH + h
  const int lane = (int)threadIdx.x & 63;
  const int plane = row / HH;
  const int h = row % HH;
  const int b = plane / CC;
  const int ch = plane % CC;
  const int g = ch >> 3;
  const int cl = ch & 7;

  const int tbase = (b * GG + g) * 72 + cl * 9; // wave-uniform
  const float* rowp = feat + (size_t)plane * HWSZ + h * WW;
  float* orow = out + (size_t)plane * HWSZ + h * WW;
  const float* rowlane = rowp + lane; // per-lane base

  const float v0 = rowlane[0];
  const float v1 = rowlane[64];
  const float v2 = rowlane[128];
  float a0 = 0.0f, a1 = 0.0f, a2 = 0.0f;

#pragma unroll
  for (int k = 0; k < 9; ++k) {
    const int ki = k / 3, kj = k % 3; // compile-time
    const bool hv = (h >= ki) & (h < HM + ki); // wave-uniform
    if (hv) {
      const int oo = g_rel[tbase + k];   // scalar load
      const float sc = g_scl[tbase + k]; // scalar load
      // w-validity: w-kj in [0,190). Sub0 (w=lane): invalid iff lane<kj.
      // Sub1 (w in [64,128)): always valid. Sub2 (w=lane+128): invalid iff
      // lane >= 62+kj. Clamped offsets also keep every address in-bounds.
      const bool wv0 = (lane >= kj);
      const bool wv2 = (lane < 62 + kj);
      const int o0 = wv0 ? oo : 0;
      const int o2 = wv2 ? oo : 0;
      const float n0 = rowlane[o0];
      const float n1 = rowlane[oo + 64];
      const float n2 = rowlane[o2 + 128];
      // exact fp32 op order: round-to-nearest each mul; /8 folded into sc
      const float t0 = floorf(v0 * n0 * sc);
      const float t1 = floorf(v1 * n1 * sc);
      const float t2 = floorf(v2 * n2 * sc);
      a0 += wv0 ? t0 : 0.0f;
      a1 += t1;
      a2 += wv2 ? t2 : 0.0f;
    }
  }

  if (b != 0) {
    // n_valid(h,w) = cnt_h(h) * cnt_w(w), cnt = min(p,2) - max(p-189,0) + 1
    const int chn = (h < 2 ? h : 2) - (h > 189 ? h - 189 : 0) + 1; // uniform
    const int w0 = lane, w2 = lane + 128;
    const int cw0 = (w0 < 2 ? w0 : 2) + 1; // w0 <= 63 < 189
    const int cw2 = 3 - (w2 > 189 ? w2 - 189 : 0);
    a0 += (float)(chn * cw0) * v0;
    a1 += (float)(chn * 3) * v1;
    a2 += (float)(chn * cw2) * v2;
  }
  orow[0 + lane] = a0;
  orow[64 + lane] = a1;
  orow[128 + lane] = a2;
}

extern "C" void kernel_launch(void* const* d_in, const int* in_sizes, int n_in,
                              void* d_out, int out_size, void* d_ws,
                              size_t ws_size, hipStream_t stream) {
  const float* feat = (const float*)d_in[0];
  float* out = (float*)d_out;
  (void)d_ws;
  (void)ws_size;

  phase1a_kernel<<<NTRIPLE * SPLIT, 256, 0, stream>>>(feat);
  phase1b_kernel<<<(NTRIPLE + 63) / 64, 64, 0, stream>>>();

  const int rows = BB * CC * HH; // 49152, /4 rows per block
  phase2_kernel<<<rows / 4, 256, 0, stream>>>(feat, out);
}

// Round 5
// 140.613 us; speedup vs baseline: 1.8230x; 1.0362x over previous
//
#include <hip/hip_runtime.h>
#include <hip/hip_bf16.h>
#include <math.h>

// Problem constants (B=2, C=128, G=16, Cg=8, K=3, H=W=192)
#define BB 2
#define CC 128
#define GG 16
#define CG 8
#define HH 192
#define WW 192
#define HM 190
#define WM 190
#define LL (HM * WM)          // 36100
#define HWSZ (HH * WW)        // 36864
#define NTRIPLE (BB * GG * 9) // 288
#define SPLIT 6               // row slices for phase1 parallelism
#define ROWS_PER_SLICE 32     // 6*32 >= 190

// 4-byte-aligned float4 for unaligned (dword-aligned) vector loads.
typedef float float4a __attribute__((ext_vector_type(4), aligned(4)));
typedef float float4v __attribute__((ext_vector_type(4)));

// Module-owned scratch (d_ws size unverified; writing it corrupted the
// harness pristine input copy in R0). Everything below is fully rewritten
// on every call before being read (same stream) -> identical work per call.
__device__ float g_part[NTRIPLE * SPLIT * 36]; // per-slice partial sums
__device__ int g_rel[BB * GG * 72];            // phase2: neighbor rel offset
__device__ float g_scl[BB * GG * 72];          // phase2: c_max/8

// -------- Phase 1a: per (b,g,j,rowslice) partial Gram sums, float4 --------
// Each thread handles 4 consecutive x per iter: 8 dwordx4 loads feed 144
// FMAs (R4 version was latency-bound on 32 scalar loads per 4 px).
__global__ __launch_bounds__(256) void phase1a_kernel(
    const float* __restrict__ feat) {
  const int tri = blockIdx.x / SPLIT; // 0..287
  const int sl = blockIdx.x % SPLIT;
  const int b = tri / (GG * 9);
  const int rem = tri % (GG * 9);
  const int g = rem / 9;
  const int j = rem % 9;

  const float* base[8];
#pragma unroll
  for (int d = 0; d < 8; ++d) {
    const int f = j * 8 + d;
    const int c = f / 9;
    const int k = f % 9;
    const int ki = k / 3, kj = k % 3;
    base[d] = feat + (size_t)(b * CC + g * CG + c) * HWSZ + ki * WW + kj;
  }

  float acc[36];
#pragma unroll
  for (int i = 0; i < 36; ++i) acc[i] = 0.0f;

  const int y0 = sl * ROWS_PER_SLICE;
  const int y1 = (y0 + ROWS_PER_SLICE < HM) ? y0 + ROWS_PER_SLICE : HM;
  const int ng = (y1 - y0) * 48; // 48 groups of 4 px per row (190 cols)

  for (int gi = (int)threadIdx.x; gi < ng; gi += 256) {
    const int y = y0 + gi / 48;
    const int xg = gi % 48;
    // Group 47 covers x=188,189 only; load shifted to x=186 so the dwordx4
    // stays in-bounds (max addr (y+2)*192 + 2 + 189 = 36863 < 36864), then
    // zero the two duplicate elements (x=186,187 belong to group 46).
    const bool tail = (xg == 47);
    const int xL = tail ? 186 : xg * 4;
    const int ro = y * WW + xL;
    float4a v[8];
#pragma unroll
    for (int d = 0; d < 8; ++d) v[d] = *(const float4a*)(base[d] + ro);
    if (tail) {
#pragma unroll
      for (int d = 0; d < 8; ++d) {
        v[d].x = 0.0f;
        v[d].y = 0.0f;
      }
    }
#pragma unroll
    for (int d = 0; d < 8; ++d)
      acc[d] += v[d].x * v[d].x + v[d].y * v[d].y + v[d].z * v[d].z +
                v[d].w * v[d].w;
    int p = 8;
#pragma unroll
    for (int c = 0; c < 8; ++c)
#pragma unroll
      for (int d = c + 1; d < 8; ++d) {
        acc[p] += v[c].x * v[d].x + v[c].y * v[d].y + v[c].z * v[d].z +
                  v[c].w * v[d].w;
        ++p;
      }
  }

  // Wave shuffle reduce (64 lanes) then LDS across 4 waves.
  __shared__ float red[36 * 4];
  const int lane = threadIdx.x & 63;
  const int wave = threadIdx.x >> 6;
#pragma unroll
  for (int i = 0; i < 36; ++i) {
    float v = acc[i];
    for (int o = 32; o > 0; o >>= 1) v += __shfl_down(v, o, 64);
    if (lane == 0) red[i * 4 + wave] = v;
  }
  __syncthreads();
  if (threadIdx.x < 36) {
    const int i = threadIdx.x;
    g_part[(tri * SPLIT + sl) * 36 + i] =
        red[i * 4] + red[i * 4 + 1] + red[i * 4 + 2] + red[i * 4 + 3];
  }
}

// -------- Phase 1b: reduce slices, 8x8 argmin, emit phase2 tables ---------
__global__ __launch_bounds__(64) void phase1b_kernel() {
  const int tri = blockIdx.x * 64 + (int)threadIdx.x;
  if (tri >= NTRIPLE) return;
  const int b = tri / (GG * 9);
  const int rem = tri % (GG * 9);
  const int g = rem / 9;
  const int j = rem % 9;

  float tot[36];
#pragma unroll
  for (int i = 0; i < 36; ++i) tot[i] = 0.0f;
  for (int s = 0; s < SPLIT; ++s)
#pragma unroll
    for (int i = 0; i < 36; ++i) tot[i] += g_part[(tri * SPLIT + s) * 36 + i];

  float sq[8], gm[8][8];
#pragma unroll
  for (int i = 0; i < 8; ++i) sq[i] = tot[i];
  {
    int p = 8;
    for (int c = 0; c < 8; ++c)
      for (int d = c + 1; d < 8; ++d) {
        gm[c][d] = tot[p];
        gm[d][c] = tot[p];
        ++p;
      }
  }
  // per-row argmin with inf diagonal, first-occurrence tie-break
  int nn[8];
  for (int c = 0; c < 8; ++c) {
    float best = INFINITY;
    int bi = 0;
    for (int d = 0; d < 8; ++d) {
      if (d == c) continue;
      const float d2 = sq[c] + sq[d] - 2.0f * gm[c][d];
      if (d2 < best) {
        best = d2;
        bi = d;
      }
    }
    nn[c] = bi;
  }
  int um = 0;
  for (int c = 0; c < 8; ++c) um = um > nn[c] ? um : nn[c];
  int cnt = 0;
  for (int c = 0; c < 8; ++c) cnt += (nn[c] == um) ? 1 : 0;

  // scale = c_max/8 (exact: int * power of two); rel = neighbor offset
  // relative to the query pixel, constant over (h,w).
  const float sc = (float)cnt * 0.125f;
  const int fn = j * 8 + um;
  const int cn = fn / 9;
  const int kn = fn % 9;
  const int kin = kn / 3, kjn = kn % 3;
  for (int d = 0; d < 8; ++d) {
    const int f = j * 8 + d;
    const int cl = f / 9;
    const int k = f % 9;
    const int ki = k / 3, kj = k % 3;
    const int rel = (cn - cl) * HWSZ + (kin - ki) * WW + (kjn - kj);
    const int tix = (b * GG + g) * 72 + f;
    g_rel[tix] = rel;
    g_scl[tix] = sc;
  }
}

// -------- Phase 2 main: interior float4 groups, no masks ------------------
// Interior (h in [2,190), w0 in [4,188)): all 9 k's valid for all 4 px, all
// neighbor dwordx4 loads provably in-bounds (row h+dy in [0,191], col
// w0+dx+e in [2,189]). Edge groups are skipped here and written by
// phase2_edge (disjoint -> no race, deterministic).
__global__ __launch_bounds__(256) void phase2_main_kernel(
    const float* __restrict__ feat, float* __restrict__ out) {
  const int plane = blockIdx.x / 36; // 36 blocks per plane (9216 float4)
  const int inner = (blockIdx.x % 36) * 1024 + (int)threadIdx.x * 4;
  const int h = inner / WW;
  const int w0 = inner % WW;
  if (h < 2 || h >= HM || w0 < 4 || w0 >= 188) return;

  const int g = (plane % CC) >> 3;
  const int cl = (plane % CC) & 7;
  const int tbase = ((plane / CC) * GG + g) * 72 + cl * 9;

  int rel[9];
  float scl[9];
#pragma unroll
  for (int k = 0; k < 9; ++k) {
    rel[k] = g_rel[tbase + k];
    scl[k] = g_scl[tbase + k];
  }

  const float* p = feat + (size_t)plane * HWSZ + inner;
  const float4v v = *(const float4v*)p;
  float4v acc = {0.0f, 0.0f, 0.0f, 0.0f};
#pragma unroll
  for (int k = 0; k < 9; ++k) {
    const float4a n = *(const float4a*)(p + rel[k]);
    const float s = scl[k];
    // exact reference op order: round(v*n*cm)/8 == round(v*n*(cm/8))
    acc.x += floorf(v.x * n.x * s);
    acc.y += floorf(v.y * n.y * s);
    acc.z += floorf(v.z * n.z * s);
    acc.w += floorf(v.w * n.w * s);
  }
  if (plane >= CC) { // b != 0; interior => n_valid = 9
    acc.x += 9.0f * v.x;
    acc.y += 9.0f * v.y;
    acc.z += 9.0f * v.z;
    acc.w += 9.0f * v.w;
  }
  *(float4v*)(out + (size_t)plane * HWSZ + inner) = acc;
}

// -------- Phase 2 edge: border pixels, clamped scalar path ----------------
// 2272 px per plane: rows {0,1,190,191} (768) + cols {0..3,188..191} for
// h in [2,190) (1504). 256 planes * 2272 = 581632 = 2272 blocks * 256.
__global__ __launch_bounds__(256) void phase2_edge_kernel(
    const float* __restrict__ feat, float* __restrict__ out) {
  const int gid = blockIdx.x * 256 + (int)threadIdx.x;
  const int plane = gid / 2272;
  const int ei = gid % 2272;
  int h, w;
  if (ei < 768) {
    const int r = ei / WW; // 0..3
    h = (r < 2) ? r : r + 188; // 0,1,190,191
    w = ei % WW;
  } else {
    const int e2 = ei - 768;
    h = 2 + (e2 >> 3);
    const int w8 = e2 & 7;
    w = (w8 < 4) ? w8 : w8 + 184; // 0..3, 188..191
  }
  const int g = (plane % CC) >> 3;
  const int cl = (plane % CC) & 7;
  const int tbase = ((plane / CC) * GG + g) * 72 + cl * 9;

  int rel[9];
  float scl[9];
#pragma unroll
  for (int k = 0; k < 9; ++k) {
    rel[k] = g_rel[tbase + k];
    scl[k] = g_scl[tbase + k];
  }

  const int idx = plane * HWSZ + h * WW + w;
  const float* p = feat + idx;
  const float v = *p;
  float acc = 0.0f;
  int nv = 0;
#pragma unroll
  for (int k = 0; k < 9; ++k) {
    const int ki = k / 3, kj = k % 3; // compile-time
    const int y = h - ki, x = w - kj;
    const bool valid = ((unsigned)y < (unsigned)HM) & ((unsigned)x < (unsigned)WM);
    const int o = valid ? rel[k] : 0; // clamp keeps the load in-bounds
    const float n = p[o];
    const float fl = floorf(v * n * scl[k]);
    acc += valid ? fl : 0.0f;
    nv += valid ? 1 : 0;
  }
  if (plane >= CC) acc += (float)nv * v;
  out[idx] = acc;
}

extern "C" void kernel_launch(void* const* d_in, const int* in_sizes, int n_in,
                              void* d_out, int out_size, void* d_ws,
                              size_t ws_size, hipStream_t stream) {
  const float* feat = (const float*)d_in[0];
  float* out = (float*)d_out;
  (void)d_ws;
  (void)ws_size;

  phase1a_kernel<<<NTRIPLE * SPLIT, 256, 0, stream>>>(feat);
  phase1b_kernel<<<(NTRIPLE + 63) / 64, 64, 0, stream>>>();

  phase2_main_kernel<<<BB * CC * 36, 256, 0, stream>>>(feat, out);
  phase2_edge_kernel<<<2272, 256, 0, stream>>>(feat, out);
}

// Round 6
// 136.995 us; speedup vs baseline: 1.8712x; 1.0264x over previous
//
#include <hip/hip_runtime.h>
#include <hip/hip_bf16.h>
#include <math.h>

// Problem constants (B=2, C=128, G=16, Cg=8, K=3, H=W=192)
#define BB 2
#define CC 128
#define GG 16
#define CG 8
#define HH 192
#define WW 192
#define HM 190
#define WM 190
#define LL (HM * WM)          // 36100
#define HWSZ (HH * WW)        // 36864
#define NTRIPLE (BB * GG * 9) // 288
#define SPLIT 6               // row slices for phase1 parallelism
#define ROWS_PER_SLICE 32     // 6*32 >= 190

// 4-byte-aligned float4 for unaligned (dword-aligned) vector loads.
typedef float float4a __attribute__((ext_vector_type(4), aligned(4)));
typedef float float4v __attribute__((ext_vector_type(4)));

// Module-owned scratch (d_ws size unverified; writing it corrupted the
// harness pristine input copy in R0). Everything below is fully rewritten
// on every call before being read (same stream) -> identical work per call.
__device__ float g_part[NTRIPLE * SPLIT * 36]; // per-slice partial sums
__device__ int g_rel[BB * GG * 72];            // phase2: neighbor rel offset
__device__ float g_scl[BB * GG * 72];          // phase2: c_max/8

// -------- Phase 1a: per (b,g,j,rowslice) partial Gram sums, float4 --------
// XCD-locality swizzle: all 54 blocks (9 j x 6 slices) of one (b,g) unit
// land on ONE XCD (blockIdx%8 round-robin): unit data = 1.2 MB, 4 units/XCD
// = 4.8 MB ~ L2 -> the 9x logical re-read of channel data hits L2 (~200cy)
// instead of thrashing to L3 (~700cy). R5 showed FETCH=compulsory but wall
// 4x above the VALU+L2 floor -> un-hidden L3 latency was the bottleneck.
__global__ __launch_bounds__(256) void phase1a_kernel(
    const float* __restrict__ feat) {
  const int B = blockIdx.x;      // 0..1727
  const int xcd = B & 7;
  const int slot = B >> 3;       // 0..215
  const int unit = xcd * 4 + slot / 54; // (b,g) composite, 0..31
  const int r = slot % 54;
  const int j = r / 6;
  const int sl = r % 6;
  const int b = unit >> 4;
  const int g = unit & 15;

  const float* base[8];
#pragma unroll
  for (int d = 0; d < 8; ++d) {
    const int f = j * 8 + d;
    const int c = f / 9;
    const int k = f % 9;
    const int ki = k / 3, kj = k % 3;
    base[d] = feat + (size_t)(b * CC + g * CG + c) * HWSZ + ki * WW + kj;
  }

  float acc[36];
#pragma unroll
  for (int i = 0; i < 36; ++i) acc[i] = 0.0f;

  const int y0 = sl * ROWS_PER_SLICE;
  const int y1 = (y0 + ROWS_PER_SLICE < HM) ? y0 + ROWS_PER_SLICE : HM;
  const int ng = (y1 - y0) * 48; // 48 groups of 4 px per row (190 cols)

  for (int gi = (int)threadIdx.x; gi < ng; gi += 256) {
    const int y = y0 + gi / 48;
    const int xg = gi % 48;
    // Group 47 covers x=188,189 only; load shifted to x=186 so the dwordx4
    // stays in-bounds, then zero the two duplicate elements.
    const bool tail = (xg == 47);
    const int xL = tail ? 186 : xg * 4;
    const int ro = y * WW + xL;
    float4a v[8];
#pragma unroll
    for (int d = 0; d < 8; ++d) v[d] = *(const float4a*)(base[d] + ro);
    if (tail) {
#pragma unroll
      for (int d = 0; d < 8; ++d) {
        v[d].x = 0.0f;
        v[d].y = 0.0f;
      }
    }
#pragma unroll
    for (int d = 0; d < 8; ++d)
      acc[d] += v[d].x * v[d].x + v[d].y * v[d].y + v[d].z * v[d].z +
                v[d].w * v[d].w;
    int p = 8;
#pragma unroll
    for (int c = 0; c < 8; ++c)
#pragma unroll
      for (int d = c + 1; d < 8; ++d) {
        acc[p] += v[c].x * v[d].x + v[c].y * v[d].y + v[c].z * v[d].z +
                  v[c].w * v[d].w;
        ++p;
      }
  }

  // Wave shuffle reduce (64 lanes) then LDS across 4 waves.
  __shared__ float red[36 * 4];
  const int lane = threadIdx.x & 63;
  const int wave = threadIdx.x >> 6;
#pragma unroll
  for (int i = 0; i < 36; ++i) {
    float v = acc[i];
    for (int o = 32; o > 0; o >>= 1) v += __shfl_down(v, o, 64);
    if (lane == 0) red[i * 4 + wave] = v;
  }
  __syncthreads();
  if (threadIdx.x < 36) {
    const int i = threadIdx.x;
    const int tri = unit * 9 + j;
    g_part[(tri * SPLIT + sl) * 36 + i] =
        red[i * 4] + red[i * 4 + 1] + red[i * 4 + 2] + red[i * 4 + 3];
  }
}

// -------- Phase 1b: reduce slices, 8x8 argmin, emit phase2 tables ---------
__global__ __launch_bounds__(64) void phase1b_kernel() {
  const int tri = blockIdx.x * 64 + (int)threadIdx.x;
  if (tri >= NTRIPLE) return;
  const int b = tri / (GG * 9);
  const int rem = tri % (GG * 9);
  const int g = rem / 9;
  const int j = rem % 9;

  float tot[36];
#pragma unroll
  for (int i = 0; i < 36; ++i) tot[i] = 0.0f;
  for (int s = 0; s < SPLIT; ++s)
#pragma unroll
    for (int i = 0; i < 36; ++i) tot[i] += g_part[(tri * SPLIT + s) * 36 + i];

  float sq[8], gm[8][8];
#pragma unroll
  for (int i = 0; i < 8; ++i) sq[i] = tot[i];
  {
    int p = 8;
    for (int c = 0; c < 8; ++c)
      for (int d = c + 1; d < 8; ++d) {
        gm[c][d] = tot[p];
        gm[d][c] = tot[p];
        ++p;
      }
  }
  // per-row argmin with inf diagonal, first-occurrence tie-break
  int nn[8];
  for (int c = 0; c < 8; ++c) {
    float best = INFINITY;
    int bi = 0;
    for (int d = 0; d < 8; ++d) {
      if (d == c) continue;
      const float d2 = sq[c] + sq[d] - 2.0f * gm[c][d];
      if (d2 < best) {
        best = d2;
        bi = d;
      }
    }
    nn[c] = bi;
  }
  int um = 0;
  for (int c = 0; c < 8; ++c) um = um > nn[c] ? um : nn[c];
  int cnt = 0;
  for (int c = 0; c < 8; ++c) cnt += (nn[c] == um) ? 1 : 0;

  // scale = c_max/8 (exact: int * power of two); rel = neighbor offset
  // relative to the query pixel, constant over (h,w).
  const float sc = (float)cnt * 0.125f;
  const int fn = j * 8 + um;
  const int cn = fn / 9;
  const int kn = fn % 9;
  const int kin = kn / 3, kjn = kn % 3;
  for (int d = 0; d < 8; ++d) {
    const int f = j * 8 + d;
    const int cl = f / 9;
    const int k = f % 9;
    const int ki = k / 3, kj = k % 3;
    const int rel = (cn - cl) * HWSZ + (kin - ki) * WW + (kjn - kj);
    const int tix = (b * GG + g) * 72 + f;
    g_rel[tix] = rel;
    g_scl[tix] = sc;
  }
}

// -------- Phase 2 main: interior float4 groups, no masks ------------------
// XCD-locality swizzle: all 144 blocks (8 planes x 18) of one (b,g) unit on
// one XCD -> the 10x logical read of the unit's 1.2 MB channel group stays
// L2-resident. 2 float4 groups per thread amortize the table prologue.
// Edge pixels are skipped here and written by phase2_edge (disjoint sets).
__global__ __launch_bounds__(256) void phase2_main_kernel(
    const float* __restrict__ feat, float* __restrict__ out) {
  const int B = blockIdx.x;      // 0..4607
  const int xcd = B & 7;
  const int slot = B >> 3;       // 0..575
  const int unit = xcd * 4 + slot / 144; // (b,g) composite, 0..31
  const int r = slot % 144;
  const int cl = r / 18;         // local channel 0..7
  const int blk = r % 18;        // 18 x 2048 px = one plane
  const int plane = unit * 8 + cl; // == b*CC + ch

  const int tbase = unit * 72 + cl * 9;
  int rel[9];
  float scl[9];
#pragma unroll
  for (int k = 0; k < 9; ++k) {
    rel[k] = g_rel[tbase + k];
    scl[k] = g_scl[tbase + k];
  }

  const float* pb = feat + (size_t)plane * HWSZ;
  float* ob = out + (size_t)plane * HWSZ;
  const bool b1 = (unit >= GG); // b != 0
  const int i0 = blk * 2048 + (int)threadIdx.x * 4;

#pragma unroll
  for (int gidx = 0; gidx < 2; ++gidx) {
    const int inner = i0 + gidx * 1024;
    const int h = inner / WW;
    const int w0 = inner % WW;
    if (h >= 2 && h < HM && w0 >= 4 && w0 < 188) {
      const float* p = pb + inner;
      const float4v v = *(const float4v*)p;
      float4v acc = {0.0f, 0.0f, 0.0f, 0.0f};
#pragma unroll
      for (int k = 0; k < 9; ++k) {
        const float4a n = *(const float4a*)(p + rel[k]);
        const float s = scl[k];
        // exact reference op order: round(v*n*cm)/8 == round(v*n*(cm/8))
        acc.x += floorf(v.x * n.x * s);
        acc.y += floorf(v.y * n.y * s);
        acc.z += floorf(v.z * n.z * s);
        acc.w += floorf(v.w * n.w * s);
      }
      if (b1) { // interior => n_valid = 9
        acc.x += 9.0f * v.x;
        acc.y += 9.0f * v.y;
        acc.z += 9.0f * v.z;
        acc.w += 9.0f * v.w;
      }
      *(float4v*)(ob + inner) = acc;
    }
  }
}

// -------- Phase 2 edge: border pixels, clamped scalar path ----------------
// 2272 px per plane: rows {0,1,190,191} (768) + cols {0..3,188..191} for
// h in [2,190) (1504). 256 planes * 2272 = 581632 = 2272 blocks * 256.
__global__ __launch_bounds__(256) void phase2_edge_kernel(
    const float* __restrict__ feat, float* __restrict__ out) {
  const int gid = blockIdx.x * 256 + (int)threadIdx.x;
  const int plane = gid / 2272;
  const int ei = gid % 2272;
  int h, w;
  if (ei < 768) {
    const int r = ei / WW; // 0..3
    h = (r < 2) ? r : r + 188; // 0,1,190,191
    w = ei % WW;
  } else {
    const int e2 = ei - 768;
    h = 2 + (e2 >> 3);
    const int w8 = e2 & 7;
    w = (w8 < 4) ? w8 : w8 + 184; // 0..3, 188..191
  }
  const int g = (plane % CC) >> 3;
  const int cl = (plane % CC) & 7;
  const int tbase = ((plane / CC) * GG + g) * 72 + cl * 9;

  int rel[9];
  float scl[9];
#pragma unroll
  for (int k = 0; k < 9; ++k) {
    rel[k] = g_rel[tbase + k];
    scl[k] = g_scl[tbase + k];
  }

  const int idx = plane * HWSZ + h * WW + w;
  const float* p = feat + idx;
  const float v = *p;
  float acc = 0.0f;
  int nv = 0;
#pragma unroll
  for (int k = 0; k < 9; ++k) {
    const int ki = k / 3, kj = k % 3; // compile-time
    const int y = h - ki, x = w - kj;
    const bool valid = ((unsigned)y < (unsigned)HM) & ((unsigned)x < (unsigned)WM);
    const int o = valid ? rel[k] : 0; // clamp keeps the load in-bounds
    const float n = p[o];
    const float fl = floorf(v * n * scl[k]);
    acc += valid ? fl : 0.0f;
    nv += valid ? 1 : 0;
  }
  if (plane >= CC) acc += (float)nv * v;
  out[idx] = acc;
}

extern "C" void kernel_launch(void* const* d_in, const int* in_sizes, int n_in,
                              void* d_out, int out_size, void* d_ws,
                              size_t ws_size, hipStream_t stream) {
  const float* feat = (const float*)d_in[0];
  float* out = (float*)d_out;
  (void)d_ws;
  (void)ws_size;

  phase1a_kernel<<<NTRIPLE * SPLIT, 256, 0, stream>>>(feat);
  phase1b_kernel<<<(NTRIPLE + 63) / 64, 64, 0, stream>>>();

  phase2_main_kernel<<<BB * CC * 18, 256, 0, stream>>>(feat, out);
  phase2_edge_kernel<<<2272, 256, 0, stream>>>(feat, out);
}